// Round 19
// baseline (49.119 us; speedup 1.0000x reference)
//
#include <hip/hip_runtime.h>
#include <hip/hip_bf16.h>
#include <math.h>

#define NH 1024
#define SEQ 1024
#define BATCH 2
#define NHEAD 16
#define DHEAD 64

typedef __attribute__((ext_vector_type(8))) short short8;
typedef __attribute__((ext_vector_type(4))) float f32x4;
typedef __attribute__((ext_vector_type(2))) float f32x2;

__device__ __forceinline__ unsigned short f2bf(float f) {
    unsigned u = __builtin_bit_cast(unsigned, f);
    unsigned r = 0x7FFFu + ((u >> 16) & 1u);
    u += r;
    return (unsigned short)(u >> 16);
}
__device__ __forceinline__ unsigned pk_bf2(float lo, float hi) {
    return (unsigned)f2bf(lo) | ((unsigned)f2bf(hi) << 16);
}
__device__ __forceinline__ unsigned cvtpk_bf16(float lo, float hi) {
    unsigned r;
    asm("v_cvt_pk_bf16_f32 %0, %1, %2" : "=v"(r) : "v"(lo), "v"(hi));
    return r;
}

typedef __attribute__((address_space(1))) const unsigned int as1_uint;
typedef __attribute__((address_space(3))) unsigned int as3_uint;
__device__ __forceinline__ void gload16(const void* g, void* l) {
    __builtin_amdgcn_global_load_lds((as1_uint*)g, (as3_uint*)l, 16, 0, 0);
}

// ================= Kernel 1: fused LN (wave-per-row) + weight prep + mask prep =================
__global__ __launch_bounds__(256) void k_pre(
    const float* __restrict__ x, const float* __restrict__ ln_g,
    const float* __restrict__ ln_b, const float* __restrict__ Wv,
    const float* __restrict__ Wq, const float* __restrict__ Wk,
    const float* __restrict__ mask,
    unsigned short* __restrict__ xnb, unsigned short* __restrict__ WvT,
    unsigned short* __restrict__ WqkT, float* __restrict__ maskf)
{
    __shared__ __align__(16) unsigned char smem[16704];
    int bid = blockIdx.x;
    int t = threadIdx.x;

    if (bid < BATCH * SEQ / 4) {
        int w = t >> 6, lane = t & 63;
        int row = bid * 4 + w;
        float4 xv[4];
#pragma unroll
        for (int c = 0; c < 4; ++c)
            xv[c] = *(const float4*)(x + (size_t)row * NH + c * 256 + lane * 4);
        float s = 0.f, ss = 0.f;
#pragma unroll
        for (int c = 0; c < 4; ++c) {
            s  += xv[c].x + xv[c].y + xv[c].z + xv[c].w;
            ss += xv[c].x*xv[c].x + xv[c].y*xv[c].y + xv[c].z*xv[c].z + xv[c].w*xv[c].w;
        }
#pragma unroll
        for (int off = 32; off > 0; off >>= 1) {
            s  += __shfl_xor(s, off);
            ss += __shfl_xor(ss, off);
        }
        float mu  = s * (1.0f / NH);
        float var = ss * (1.0f / NH) - mu * mu;
        float rstd = rsqrtf(var + 1e-5f);
#pragma unroll
        for (int c = 0; c < 4; ++c) {
            float4 gv = *(const float4*)(ln_g + c * 256 + lane * 4);
            float4 bv2 = *(const float4*)(ln_b + c * 256 + lane * 4);
            float o0 = (xv[c].x - mu) * rstd * gv.x + bv2.x;
            float o1 = (xv[c].y - mu) * rstd * gv.y + bv2.y;
            float o2 = (xv[c].z - mu) * rstd * gv.z + bv2.z;
            float o3 = (xv[c].w - mu) * rstd * gv.w + bv2.w;
            uint2 u;
            u.x = pk_bf2(o0, o1);
            u.y = pk_bf2(o2, o3);
            *(uint2*)(xnb + (size_t)row * NH + c * 256 + lane * 4) = u;
        }
        return;
    }
    int u = bid - BATCH * SEQ / 4;
    if (u < 256) {
        float (*T)[65] = (float(*)[65])smem;
        int k0 = (u >> 4) * 64, n0 = (u & 15) * 64;
        int row = t >> 2, c4 = t & 3;
#pragma unroll
        for (int s = 0; s < 4; ++s) {
            float4 v = *(const float4*)(Wv + (size_t)(k0 + row) * NH + n0 + c4 * 16 + s * 4);
            *(float4*)&T[row][c4 * 16 + s * 4] = v;
        }
        __syncthreads();
        unsigned short tmp[16] __attribute__((aligned(16)));
#pragma unroll
        for (int s = 0; s < 16; ++s) tmp[s] = f2bf(T[c4 * 16 + s][row]);
        unsigned short* dst = WvT + (size_t)(n0 + row) * NH + k0 + c4 * 16;
        *(short8*)dst = *(const short8*)&tmp[0];
        *(short8*)(dst + 8) = *(const short8*)&tmp[8];
    } else if (u < 512) {
        int i = (u - 256) * 256 + t;
        int n = i >> 10, k = i & 1023;
        float v = (n < 16) ? Wq[k * 16 + n] : (n < 32 ? Wk[k * 16 + (n - 16)] : 0.0f);
        WqkT[i] = f2bf(v);
    } else {
        int i = (u - 512) * 256 + t;
        maskf[i] = (1.0f - mask[i]) * 0.044194173824159216f * 0.69314718055994531f;
    }
}

// ================= Kernel 2: MFMA GEMM BM=32, race-free counted-vmcnt pipeline =================
// v path: V pre-scaled by maskf (folds mask+scale+ln2 into V rows).
// qk path: writes qT and score tables Ak = -(cs+sn)*L2E*k, Bk = cs*L2E*k, Ek = exp2((cs+sn)*L2E*k).
__global__ __launch_bounds__(256) void k_gemm(
    const unsigned short* __restrict__ xnb,
    const unsigned short* __restrict__ WvT, const unsigned short* __restrict__ WqkT,
    const float* __restrict__ bv, const float* __restrict__ bq, const float* __restrict__ bk,
    const float* __restrict__ angle, const float* __restrict__ maskf,
    unsigned short* __restrict__ vt, float* __restrict__ qT,
    float* __restrict__ Ak, float* __restrict__ Bk, float* __restrict__ Ek)
{
    __shared__ unsigned short lds[2][6144];  // per buf: A 32x64 @0 (2048), B 64x64 @2048 (4096)
    int t = threadIdx.x, w = t >> 6, lane = t & 63, g = lane >> 4, r = lane & 15;
    // XCD-bijective swizzle: 1088 = 8 * 136
    int bid = blockIdx.x;
    int lb = (bid & 7) * 136 + (bid >> 3);
    int nt_ = lb % 17, mt = lb / 17;          // mt in [0,64)
    int i0 = mt * 32, n0 = nt_ * 64;
    const unsigned short* Bsrc = (nt_ < 16) ? (WvT + (size_t)n0 * NH) : WqkT;

    f32x4 acc[2];
    acc[0] = (f32x4)(0.0f);
    acc[1] = (f32x4)(0.0f);

    auto stage = [&](int buf, int k0) {
        {
            int o = w * 1024 + lane * 16;            // 4KB A region
            int rr = o >> 7, cb = o & 127;
            int sc = (cb ^ ((rr & 7) << 4)) >> 1;
            gload16(xnb + (size_t)(i0 + rr) * NH + k0 + sc, &lds[buf][o >> 1]);
        }
#pragma unroll
        for (int i = 0; i < 2; ++i) {
            int o = i * 4096 + w * 1024 + lane * 16; // 8KB B region
            int rr = o >> 7, cb = o & 127;
            int sc = (cb ^ ((rr & 7) << 4)) >> 1;
            gload16(Bsrc + (size_t)rr * NH + k0 + sc, &lds[buf][2048 + (o >> 1)]);
        }
    };

    int mbase = (w >> 1) * 16, nbase = (w & 1) * 32;
    int swz = (r & 7) << 4;

    auto compute = [&](int buf) {
        const unsigned short* As = lds[buf];
        const unsigned short* Bs = lds[buf] + 2048;
#pragma unroll
        for (int ks = 0; ks < 2; ++ks) {
            int kbyte = ks * 64 + g * 16;
            int kb = kbyte ^ swz;
            short8 af;
            {
                int row = mbase + r;
                af = *(const short8*)(As + ((row * 128 + kb) >> 1));
            }
            short8 bfm[2];
#pragma unroll
            for (int nf = 0; nf < 2; ++nf) {
                int rowB = nbase + nf * 16 + r;
                bfm[nf] = *(const short8*)(Bs + ((rowB * 128 + kb) >> 1));
            }
#pragma unroll
            for (int nf = 0; nf < 2; ++nf)
                acc[nf] = __builtin_amdgcn_mfma_f32_16x16x32_bf16(af, bfm[nf], acc[nf], 0, 0, 0);
        }
    };

    // race-free counted-vmcnt pipeline (3 loads/tile/wave)
    stage(0, 0);
    stage(1, 64);
    asm volatile("s_waitcnt vmcnt(3)" ::: "memory");
    __builtin_amdgcn_sched_barrier(0);
    __builtin_amdgcn_s_barrier();
    int cur = 0;
#pragma unroll 1
    for (int kt = 0; kt < 14; ++kt) {
        compute(cur);
        asm volatile("s_waitcnt lgkmcnt(0)" ::: "memory");  // ds_reads of buf cur landed
        __builtin_amdgcn_sched_barrier(0);
        __builtin_amdgcn_s_barrier();
        stage(cur, (kt + 2) * 64);
        asm volatile("s_waitcnt vmcnt(3)" ::: "memory");
        __builtin_amdgcn_sched_barrier(0);
        __builtin_amdgcn_s_barrier();
        cur ^= 1;
    }
    compute(cur);
    asm volatile("s_waitcnt lgkmcnt(0)" ::: "memory");
    __builtin_amdgcn_sched_barrier(0);
    __builtin_amdgcn_s_barrier();
    asm volatile("s_waitcnt vmcnt(0)" ::: "memory");
    __builtin_amdgcn_sched_barrier(0);
    __builtin_amdgcn_s_barrier();
    compute(cur ^ 1);

    if (nt_ < 16) {
        unsigned short (*tsm)[40] = (unsigned short(*)[40])&lds[0][0];  // 5120B
        __syncthreads();
        float4 mrow4 = *(const float4*)(maskf + i0 + mbase + g * 4);
        const float* mr = (const float*)&mrow4;
#pragma unroll
        for (int nf = 0; nf < 2; ++nf) {
            float bvv = bv[n0 + nbase + nf * 16 + r];
#pragma unroll
            for (int j = 0; j < 4; ++j)
                tsm[nbase + nf * 16 + r][mbase + g * 4 + j] = f2bf((acc[nf][j] + bvv) * mr[j]);
        }
        __syncthreads();
        int b = mt >> 5;
        int jc0 = (mt & 31) * 32;
        int d = t >> 2, jb = (t & 3) * 8;
        unsigned short* dst = vt + ((size_t)((b * 16 + nt_) * 64 + d)) * 1024 + jc0 + jb;
        *(short8*)dst = *(const short8*)&tsm[d][jb];
    } else {
        const float L2E = 1.4426950408889634f;
#pragma unroll
        for (int nf = 0; nf < 2; ++nf) {
            int n = nbase + nf * 16 + r;
            if (n < 16) {
                float bb2 = bq[n];
#pragma unroll
                for (int j = 0; j < 4; ++j)
                    qT[n * 2048 + i0 + mbase + g * 4 + j] = acc[nf][j] + bb2;
            } else if (n < 32) {
                int h = n - 16;
                float bb2 = bk[h];
                float ang = angle[h];
                float csv = cosf(ang), snv = sinf(ang);
                float c2 = csv + snv;
#pragma unroll
                for (int j = 0; j < 4; ++j) {
                    int gi = i0 + mbase + g * 4 + j;
                    float val = acc[nf][j] + bb2;
                    float c2L = c2 * val * L2E;
                    Ak[h * 2048 + gi] = -c2L;
                    Bk[h * 2048 + gi] = csv * val * L2E;
                    Ek[h * 2048 + gi] = __builtin_amdgcn_exp2f(c2L);
                }
            }
        }
    }
}

// ================= Kernel 3: fused scores (table-driven) + MFMA PV + GELU + residual =================
__global__ __launch_bounds__(256, 4) void k_attn(
    const float* __restrict__ qT,
    const float* __restrict__ Ak, const float* __restrict__ Bk,
    const float* __restrict__ Ek,
    const unsigned short* __restrict__ vt, const float* __restrict__ x,
    const float* __restrict__ angle, const float* __restrict__ zfp,
    float* __restrict__ out)
{
    __shared__ __align__(16) unsigned char smem[30720];
    float* tbl = (float*)smem;                                  // [3][1024] during main loop
    float (*red)[3][32][20] = (float(*)[3][32][20])smem;        // after main loop

    int bid = blockIdx.x;
    int lb = (bid & 7) * 128 + (bid >> 3);
    int qt = lb & 31;
    int h = (lb >> 5) & 15;
    int b = lb >> 9;
    int t = threadIdx.x;
    int w = t >> 6, lane = t & 63, g = lane >> 4, r = lane & 15;
    int i0 = qt * 32;

    const float L2E = 1.4426950408889634f;
    float ang = angle[h];
    float cs = cosf(ang), sn = sinf(ang);
    float c1L = (cs - sn) * L2E, snL = sn * L2E;
    float zf = zfp[0];

    const float* qcol = qT + h * 2048 + b * 1024;
    const float* acol = Ak + h * 2048 + b * 1024;
    const float* bcol = Bk + h * 2048 + b * 1024;
    const float* ecol = Ek + h * 2048 + b * 1024;
    const unsigned short* vhead = vt + ((size_t)(b * 16 + h)) * 64 * 1024;

    int jbase = w * 256 + g * 8;

    short8 bfr[2][4];
#pragma unroll
    for (int nb = 0; nb < 4; ++nb)
        bfr[0][nb] = *(const short8*)(vhead + (size_t)(nb * 16 + r) * 1024 + jbase);

    // stage the 3 per-block score tables into LDS
    {
        float4 a = *(const float4*)(acol + t * 4);
        float4 b4 = *(const float4*)(bcol + t * 4);
        float4 e4 = *(const float4*)(ecol + t * 4);
        *(float4*)&tbl[t * 4] = a;
        *(float4*)&tbl[1024 + t * 4] = b4;
        *(float4*)&tbl[2048 + t * 4] = e4;
    }

    float qv0 = qcol[i0 + r];
    float qv1 = qcol[i0 + 16 + r];
    f32x2 c1qL = {c1L * qv0, c1L * qv1};
    f32x2 snqL = {snL * qv0, snL * qv1};
    f32x2 Eu = {__builtin_amdgcn_exp2f(-c1qL.x), __builtin_amdgcn_exp2f(-c1qL.y)};

    f32x4 acc[2][4];
#pragma unroll
    for (int m = 0; m < 2; ++m)
#pragma unroll
        for (int nb = 0; nb < 4; ++nb) acc[m][nb] = (f32x4)(0.0f);

    __syncthreads();   // tables ready

#pragma unroll 2
    for (int it = 0; it < 8; ++it) {
        int cur = it & 1, nxt = cur ^ 1;
        int j = jbase + it * 32;
        float4 aka = *(const float4*)&tbl[j];
        float4 akb = *(const float4*)&tbl[j + 4];
        float4 bka = *(const float4*)&tbl[1024 + j];
        float4 bkb = *(const float4*)&tbl[1024 + j + 4];
        float4 eea = *(const float4*)&tbl[2048 + j];
        float4 eeb = *(const float4*)&tbl[2048 + j + 4];
        if (it < 7) {
            int jn = j + 32;
#pragma unroll
            for (int nb = 0; nb < 4; ++nb)
                bfr[nxt][nb] = *(const short8*)(vhead + (size_t)(nb * 16 + r) * 1024 + jn);
        }
        float aa[8] = {aka.x, aka.y, aka.z, aka.w, akb.x, akb.y, akb.z, akb.w};
        float bb_[8] = {bka.x, bka.y, bka.z, bka.w, bkb.x, bkb.y, bkb.z, bkb.w};
        float ee_[8] = {eea.x, eea.y, eea.z, eea.w, eeb.x, eeb.y, eeb.z, eeb.w};

        unsigned a0[4], a1[4];
#pragma unroll
        for (int p = 0; p < 4; ++p) {
            float sa[2], sb[2];
#pragma unroll
            for (int q2 = 0; q2 < 2; ++q2) {
                float a_ = aa[p * 2 + q2];
                float b_ = bb_[p * 2 + q2];
                float E  = ee_[p * 2 + q2];
                f32x2 ddL = c1qL + a_;         // (real-imag)*L2E
                f32x2 imL = snqL + b_;         // imag*L2E
                f32x2 P  = Eu * E;             // exp(-dd)
                f32x2 den = P + 1.0f;
                f32x2 sg  = {__builtin_amdgcn_rcpf(den.x), __builtin_amdgcn_rcpf(den.y)};
                f32x2 compL = __builtin_elementwise_fma(ddL, sg, imL);
                f32x2 ee2 = {__builtin_amdgcn_exp2f(compL.x), __builtin_amdgcn_exp2f(compL.y)};
                f32x2 vv = ee2 + 1.0f;
                f32x2 lg = {__builtin_amdgcn_logf(vv.x), __builtin_amdgcn_logf(vv.y)};
                sa[q2] = lg.x;                 // mask*scale*ln2 pre-folded into V
                sb[q2] = lg.y;
            }
            a0[p] = cvtpk_bf16(sa[0], sa[1]);
            a1[p] = cvtpk_bf16(sb[0], sb[1]);
        }
        unsigned av0[4] = {a0[0], a0[1], a0[2], a0[3]};
        unsigned av1[4] = {a1[0], a1[1], a1[2], a1[3]};
        short8 af0 = *(short8*)av0;
        short8 af1 = *(short8*)av1;

        __builtin_amdgcn_s_setprio(1);
#pragma unroll
        for (int nb = 0; nb < 4; ++nb) {
            acc[0][nb] = __builtin_amdgcn_mfma_f32_16x16x32_bf16(af0, bfr[cur][nb], acc[0][nb], 0, 0, 0);
            acc[1][nb] = __builtin_amdgcn_mfma_f32_16x16x32_bf16(af1, bfr[cur][nb], acc[1][nb], 0, 0, 0);
        }
        __builtin_amdgcn_s_setprio(0);
    }

    __syncthreads();   // tables dead; smem becomes `red`

#pragma unroll
    for (int nb = 0; nb < 4; ++nb) {
        if (nb != w) {
            int idx = w - (w > nb ? 1 : 0);
#pragma unroll
            for (int m = 0; m < 2; ++m)
#pragma unroll
                for (int jj = 0; jj < 4; ++jj)
                    red[nb][idx][m * 16 + g * 4 + jj][r] = acc[m][nb][jj];
        }
    }
    __syncthreads();

#pragma unroll
    for (int m = 0; m < 2; ++m)
#pragma unroll
        for (int jj = 0; jj < 4; ++jj) {
            int lrow = m * 16 + g * 4 + jj;
            float c = acc[m][w][jj] + red[w][0][lrow][r]
                                    + red[w][1][lrow][r]
                                    + red[w][2][lrow][r];
            float gl = 0.5f * c * (1.0f + erff(c * 0.70710678118654752f));
            size_t base = ((size_t)(b * 1024 + i0 + lrow)) * 1024 + h * 64 + w * 16 + r;
            out[base] = x[base] + gl * zf;
        }
}

extern "C" void kernel_launch(void* const* d_in, const int* in_sizes, int n_in,
                              void* d_out, int out_size, void* d_ws, size_t ws_size,
                              hipStream_t stream) {
    const float* x      = (const float*)d_in[0];
    const float* mask   = (const float*)d_in[1];
    const float* Wq     = (const float*)d_in[2];
    const float* bq     = (const float*)d_in[3];
    const float* Wk     = (const float*)d_in[4];
    const float* bk     = (const float*)d_in[5];
    const float* Wv     = (const float*)d_in[6];
    const float* bv     = (const float*)d_in[7];
    const float* ln_g   = (const float*)d_in[8];
    const float* ln_b   = (const float*)d_in[9];
    const float* zf     = (const float*)d_in[10];
    const float* angle  = (const float*)d_in[11];
    float* out = (float*)d_out;

    unsigned short* xnb  = (unsigned short*)d_ws;   // 2M shorts
    unsigned short* vt   = xnb + 2097152;           // 2M shorts
    unsigned short* WvT  = vt + 2097152;            // 1M shorts
    unsigned short* WqkT = WvT + 1048576;           // 64K shorts
    float* qT    = (float*)(WqkT + 65536);          // 32K f32
    float* Ak    = qT + 32768;                      // 32K f32
    float* Bk    = Ak + 32768;                      // 32K f32
    float* Ek    = Bk + 32768;                      // 32K f32
    float* maskf = Ek + 32768;                      // 2K f32

    k_pre<<<BATCH * SEQ / 4 + 520, 256, 0, stream>>>(x, ln_g, ln_b, Wv, Wq, Wk, mask,
                                                     xnb, WvT, WqkT, maskf);
    k_gemm<<<64 * 17, 256, 0, stream>>>(xnb, WvT, WqkT, bv, bq, bk, angle, maskf,
                                        vt, qT, Ak, Bk, Ek);
    k_attn<<<1024, 256, 0, stream>>>(qT, Ak, Bk, Ek, vt, x, angle, zf, out);
}

// Round 20
// 47.740 us; speedup vs baseline: 1.0289x; 1.0289x over previous
//
#include <hip/hip_runtime.h>
#include <hip/hip_bf16.h>
#include <math.h>

#define NH 1024
#define SEQ 1024
#define BATCH 2
#define NHEAD 16
#define DHEAD 64

typedef __attribute__((ext_vector_type(8))) short short8;
typedef __attribute__((ext_vector_type(4))) float f32x4;
typedef __attribute__((ext_vector_type(2))) float f32x2;

__device__ __forceinline__ unsigned short f2bf(float f) {
    unsigned u = __builtin_bit_cast(unsigned, f);
    unsigned r = 0x7FFFu + ((u >> 16) & 1u);
    u += r;
    return (unsigned short)(u >> 16);
}
__device__ __forceinline__ unsigned pk_bf2(float lo, float hi) {
    return (unsigned)f2bf(lo) | ((unsigned)f2bf(hi) << 16);
}
__device__ __forceinline__ unsigned cvtpk_bf16(float lo, float hi) {
    unsigned r;
    asm("v_cvt_pk_bf16_f32 %0, %1, %2" : "=v"(r) : "v"(lo), "v"(hi));
    return r;
}

typedef __attribute__((address_space(1))) const unsigned int as1_uint;
typedef __attribute__((address_space(3))) unsigned int as3_uint;
__device__ __forceinline__ void gload16(const void* g, void* l) {
    __builtin_amdgcn_global_load_lds((as1_uint*)g, (as3_uint*)l, 16, 0, 0);
}

// ================= Kernel 1: fused LN (wave-per-row) + weight prep + mask prep =================
__global__ __launch_bounds__(256) void k_pre(
    const float* __restrict__ x, const float* __restrict__ ln_g,
    const float* __restrict__ ln_b, const float* __restrict__ Wv,
    const float* __restrict__ Wq, const float* __restrict__ Wk,
    const float* __restrict__ mask,
    unsigned short* __restrict__ xnb, unsigned short* __restrict__ WvT,
    unsigned short* __restrict__ WqkT, float* __restrict__ maskf)
{
    __shared__ __align__(16) unsigned char smem[16704];
    int bid = blockIdx.x;
    int t = threadIdx.x;

    if (bid < BATCH * SEQ / 4) {
        int w = t >> 6, lane = t & 63;
        int row = bid * 4 + w;
        float4 xv[4];
#pragma unroll
        for (int c = 0; c < 4; ++c)
            xv[c] = *(const float4*)(x + (size_t)row * NH + c * 256 + lane * 4);
        float s = 0.f, ss = 0.f;
#pragma unroll
        for (int c = 0; c < 4; ++c) {
            s  += xv[c].x + xv[c].y + xv[c].z + xv[c].w;
            ss += xv[c].x*xv[c].x + xv[c].y*xv[c].y + xv[c].z*xv[c].z + xv[c].w*xv[c].w;
        }
#pragma unroll
        for (int off = 32; off > 0; off >>= 1) {
            s  += __shfl_xor(s, off);
            ss += __shfl_xor(ss, off);
        }
        float mu  = s * (1.0f / NH);
        float var = ss * (1.0f / NH) - mu * mu;
        float rstd = rsqrtf(var + 1e-5f);
#pragma unroll
        for (int c = 0; c < 4; ++c) {
            float4 gv = *(const float4*)(ln_g + c * 256 + lane * 4);
            float4 bv2 = *(const float4*)(ln_b + c * 256 + lane * 4);
            float o0 = (xv[c].x - mu) * rstd * gv.x + bv2.x;
            float o1 = (xv[c].y - mu) * rstd * gv.y + bv2.y;
            float o2 = (xv[c].z - mu) * rstd * gv.z + bv2.z;
            float o3 = (xv[c].w - mu) * rstd * gv.w + bv2.w;
            uint2 u;
            u.x = pk_bf2(o0, o1);
            u.y = pk_bf2(o2, o3);
            *(uint2*)(xnb + (size_t)row * NH + c * 256 + lane * 4) = u;
        }
        return;
    }
    int u = bid - BATCH * SEQ / 4;
    if (u < 256) {
        float (*T)[65] = (float(*)[65])smem;
        int k0 = (u >> 4) * 64, n0 = (u & 15) * 64;
        int row = t >> 2, c4 = t & 3;
#pragma unroll
        for (int s = 0; s < 4; ++s) {
            float4 v = *(const float4*)(Wv + (size_t)(k0 + row) * NH + n0 + c4 * 16 + s * 4);
            *(float4*)&T[row][c4 * 16 + s * 4] = v;
        }
        __syncthreads();
        unsigned short tmp[16] __attribute__((aligned(16)));
#pragma unroll
        for (int s = 0; s < 16; ++s) tmp[s] = f2bf(T[c4 * 16 + s][row]);
        unsigned short* dst = WvT + (size_t)(n0 + row) * NH + k0 + c4 * 16;
        *(short8*)dst = *(const short8*)&tmp[0];
        *(short8*)(dst + 8) = *(const short8*)&tmp[8];
    } else if (u < 512) {
        int i = (u - 256) * 256 + t;
        int n = i >> 10, k = i & 1023;
        float v = (n < 16) ? Wq[k * 16 + n] : (n < 32 ? Wk[k * 16 + (n - 16)] : 0.0f);
        WqkT[i] = f2bf(v);
    } else {
        int i = (u - 512) * 256 + t;
        maskf[i] = (1.0f - mask[i]) * 0.044194173824159216f * 0.69314718055994531f;
    }
}

// ================= Kernel 2: MFMA GEMM BM=64, race-free counted-vmcnt pipeline =================
// v path: V pre-scaled by maskf. qk path: qT + score tables Ak/Bk/Ek.
__global__ __launch_bounds__(256) void k_gemm(
    const unsigned short* __restrict__ xnb,
    const unsigned short* __restrict__ WvT, const unsigned short* __restrict__ WqkT,
    const float* __restrict__ bv, const float* __restrict__ bq, const float* __restrict__ bk,
    const float* __restrict__ angle, const float* __restrict__ maskf,
    unsigned short* __restrict__ vt, float* __restrict__ qT,
    float* __restrict__ Ak, float* __restrict__ Bk, float* __restrict__ Ek)
{
    __shared__ unsigned short lds[2][8192];
    int t = threadIdx.x, w = t >> 6, lane = t & 63, g = lane >> 4, r = lane & 15;
    // XCD-bijective swizzle: 544 = 8 * 68
    int bid = blockIdx.x;
    int lb = (bid & 7) * 68 + (bid >> 3);
    int nt_ = lb % 17, mt = lb / 17;
    int i0 = mt * 64, n0 = nt_ * 64;
    const unsigned short* Bsrc = (nt_ < 16) ? (WvT + (size_t)n0 * NH) : WqkT;

    f32x4 acc[2][2];
#pragma unroll
    for (int a = 0; a < 2; ++a)
#pragma unroll
        for (int c = 0; c < 2; ++c) acc[a][c] = (f32x4)(0.0f);

    auto stage = [&](int buf, int k0) {
#pragma unroll
        for (int i = 0; i < 2; ++i) {
            int o = i * 4096 + w * 1024 + lane * 16;
            int rr = o >> 7, cb = o & 127;
            int sc = (cb ^ ((rr & 7) << 4)) >> 1;
            gload16(xnb + (size_t)(i0 + rr) * NH + k0 + sc, &lds[buf][o >> 1]);
        }
#pragma unroll
        for (int i = 0; i < 2; ++i) {
            int o = i * 4096 + w * 1024 + lane * 16;
            int rr = o >> 7, cb = o & 127;
            int sc = (cb ^ ((rr & 7) << 4)) >> 1;
            gload16(Bsrc + (size_t)rr * NH + k0 + sc, &lds[buf][4096 + (o >> 1)]);
        }
    };

    int mbase = (w >> 1) * 32, nbase = (w & 1) * 32;
    int swz = (r & 7) << 4;

    auto compute = [&](int buf) {
        const unsigned short* As = lds[buf];
        const unsigned short* Bs = lds[buf] + 4096;
#pragma unroll
        for (int ks = 0; ks < 2; ++ks) {
            int kbyte = ks * 64 + g * 16;
            int kb = kbyte ^ swz;
            short8 af[2], bfm[2];
#pragma unroll
            for (int mf = 0; mf < 2; ++mf) {
                int row = mbase + mf * 16 + r;
                af[mf] = *(const short8*)(As + ((row * 128 + kb) >> 1));
            }
#pragma unroll
            for (int nf = 0; nf < 2; ++nf) {
                int rowB = nbase + nf * 16 + r;
                bfm[nf] = *(const short8*)(Bs + ((rowB * 128 + kb) >> 1));
            }
#pragma unroll
            for (int mf = 0; mf < 2; ++mf)
#pragma unroll
                for (int nf = 0; nf < 2; ++nf)
                    acc[mf][nf] = __builtin_amdgcn_mfma_f32_16x16x32_bf16(af[mf], bfm[nf], acc[mf][nf], 0, 0, 0);
        }
    };

    // race-free counted-vmcnt pipeline (4 loads/tile/wave)
    stage(0, 0);
    stage(1, 64);
    asm volatile("s_waitcnt vmcnt(4)" ::: "memory");
    __builtin_amdgcn_sched_barrier(0);
    __builtin_amdgcn_s_barrier();
    int cur = 0;
#pragma unroll 1
    for (int kt = 0; kt < 14; ++kt) {
        compute(cur);
        asm volatile("s_waitcnt lgkmcnt(0)" ::: "memory");  // ds_reads of buf cur landed
        __builtin_amdgcn_sched_barrier(0);
        __builtin_amdgcn_s_barrier();
        stage(cur, (kt + 2) * 64);
        asm volatile("s_waitcnt vmcnt(4)" ::: "memory");
        __builtin_amdgcn_sched_barrier(0);
        __builtin_amdgcn_s_barrier();
        cur ^= 1;
    }
    compute(cur);
    asm volatile("s_waitcnt lgkmcnt(0)" ::: "memory");
    __builtin_amdgcn_sched_barrier(0);
    __builtin_amdgcn_s_barrier();
    asm volatile("s_waitcnt vmcnt(0)" ::: "memory");
    __builtin_amdgcn_sched_barrier(0);
    __builtin_amdgcn_s_barrier();
    compute(cur ^ 1);

    if (nt_ < 16) {
        unsigned short (*tsm)[72] = (unsigned short(*)[72])&lds[0][0];
        __syncthreads();
        float4 mr4[2];
        mr4[0] = *(const float4*)(maskf + i0 + mbase + g * 4);
        mr4[1] = *(const float4*)(maskf + i0 + mbase + 16 + g * 4);
#pragma unroll
        for (int nf = 0; nf < 2; ++nf) {
            float bvv = bv[n0 + nbase + nf * 16 + r];
#pragma unroll
            for (int mf = 0; mf < 2; ++mf) {
                const float* mr = (const float*)&mr4[mf];
#pragma unroll
                for (int j = 0; j < 4; ++j)
                    tsm[nbase + nf * 16 + r][mbase + mf * 16 + g * 4 + j] =
                        f2bf((acc[mf][nf][j] + bvv) * mr[j]);
            }
        }
        __syncthreads();
        int b = mt >> 4;
        int jc0 = (mt & 15) * 64;
        int d = t >> 2, jb = (t & 3) * 16;
        unsigned short* dst = vt + ((size_t)((b * 16 + nt_) * 64 + d)) * 1024 + jc0 + jb;
        *(short8*)dst = *(const short8*)&tsm[d][jb];
        *(short8*)(dst + 8) = *(const short8*)&tsm[d][jb + 8];
    } else {
        const float L2E = 1.4426950408889634f;
#pragma unroll
        for (int nf = 0; nf < 2; ++nf) {
            int n = nbase + nf * 16 + r;
            if (n < 16) {
                float bb2 = bq[n];
#pragma unroll
                for (int mf = 0; mf < 2; ++mf)
#pragma unroll
                    for (int j = 0; j < 4; ++j)
                        qT[n * 2048 + i0 + mbase + mf * 16 + g * 4 + j] = acc[mf][nf][j] + bb2;
            } else if (n < 32) {
                int h = n - 16;
                float bb2 = bk[h];
                float ang = angle[h];
                float csv = cosf(ang), snv = sinf(ang);
                float c2 = csv + snv;
#pragma unroll
                for (int mf = 0; mf < 2; ++mf)
#pragma unroll
                    for (int j = 0; j < 4; ++j) {
                        int gi = i0 + mbase + mf * 16 + g * 4 + j;
                        float val = acc[mf][nf][j] + bb2;
                        float c2L = c2 * val * L2E;
                        Ak[h * 2048 + gi] = -c2L;
                        Bk[h * 2048 + gi] = csv * val * L2E;
                        Ek[h * 2048 + gi] = __builtin_amdgcn_exp2f(c2L);
                    }
            }
        }
    }
}

// ================= Kernel 3: fused scores (table-driven) + MFMA PV + GELU + residual =================
__global__ __launch_bounds__(256, 4) void k_attn(
    const float* __restrict__ qT,
    const float* __restrict__ Ak, const float* __restrict__ Bk,
    const float* __restrict__ Ek,
    const unsigned short* __restrict__ vt, const float* __restrict__ x,
    const float* __restrict__ angle, const float* __restrict__ zfp,
    float* __restrict__ out)
{
    __shared__ __align__(16) unsigned char smem[30720];
    float* tbl = (float*)smem;                                  // [3][1024] during main loop
    float (*red)[3][32][20] = (float(*)[3][32][20])smem;        // after main loop

    int bid = blockIdx.x;
    int lb = (bid & 7) * 128 + (bid >> 3);
    int qt = lb & 31;
    int h = (lb >> 5) & 15;
    int b = lb >> 9;
    int t = threadIdx.x;
    int w = t >> 6, lane = t & 63, g = lane >> 4, r = lane & 15;
    int i0 = qt * 32;

    const float L2E = 1.4426950408889634f;
    float ang = angle[h];
    float cs = cosf(ang), sn = sinf(ang);
    float c1L = (cs - sn) * L2E, snL = sn * L2E;
    float zf = zfp[0];

    const float* qcol = qT + h * 2048 + b * 1024;
    const float* acol = Ak + h * 2048 + b * 1024;
    const float* bcol = Bk + h * 2048 + b * 1024;
    const float* ecol = Ek + h * 2048 + b * 1024;
    const unsigned short* vhead = vt + ((size_t)(b * 16 + h)) * 64 * 1024;

    int jbase = w * 256 + g * 8;

    short8 bfr[2][4];
#pragma unroll
    for (int nb = 0; nb < 4; ++nb)
        bfr[0][nb] = *(const short8*)(vhead + (size_t)(nb * 16 + r) * 1024 + jbase);

    // stage the 3 per-block score tables into LDS
    {
        float4 a = *(const float4*)(acol + t * 4);
        float4 b4 = *(const float4*)(bcol + t * 4);
        float4 e4 = *(const float4*)(ecol + t * 4);
        *(float4*)&tbl[t * 4] = a;
        *(float4*)&tbl[1024 + t * 4] = b4;
        *(float4*)&tbl[2048 + t * 4] = e4;
    }

    float qv0 = qcol[i0 + r];
    float qv1 = qcol[i0 + 16 + r];
    f32x2 c1qL = {c1L * qv0, c1L * qv1};
    f32x2 snqL = {snL * qv0, snL * qv1};
    f32x2 Eu = {__builtin_amdgcn_exp2f(-c1qL.x), __builtin_amdgcn_exp2f(-c1qL.y)};

    f32x4 acc[2][4];
#pragma unroll
    for (int m = 0; m < 2; ++m)
#pragma unroll
        for (int nb = 0; nb < 4; ++nb) acc[m][nb] = (f32x4)(0.0f);

    __syncthreads();   // tables ready

#pragma unroll 2
    for (int it = 0; it < 8; ++it) {
        int cur = it & 1, nxt = cur ^ 1;
        int j = jbase + it * 32;
        float4 aka = *(const float4*)&tbl[j];
        float4 akb = *(const float4*)&tbl[j + 4];
        float4 bka = *(const float4*)&tbl[1024 + j];
        float4 bkb = *(const float4*)&tbl[1024 + j + 4];
        float4 eea = *(const float4*)&tbl[2048 + j];
        float4 eeb = *(const float4*)&tbl[2048 + j + 4];
        if (it < 7) {
            int jn = j + 32;
#pragma unroll
            for (int nb = 0; nb < 4; ++nb)
                bfr[nxt][nb] = *(const short8*)(vhead + (size_t)(nb * 16 + r) * 1024 + jn);
        }
        float aa[8] = {aka.x, aka.y, aka.z, aka.w, akb.x, akb.y, akb.z, akb.w};
        float bb_[8] = {bka.x, bka.y, bka.z, bka.w, bkb.x, bkb.y, bkb.z, bkb.w};
        float ee_[8] = {eea.x, eea.y, eea.z, eea.w, eeb.x, eeb.y, eeb.z, eeb.w};

        unsigned a0[4], a1[4];
#pragma unroll
        for (int p = 0; p < 4; ++p) {
            float sa[2], sb[2];
#pragma unroll
            for (int q2 = 0; q2 < 2; ++q2) {
                float a_ = aa[p * 2 + q2];
                float b_ = bb_[p * 2 + q2];
                float E  = ee_[p * 2 + q2];
                f32x2 ddL = c1qL + a_;
                f32x2 imL = snqL + b_;
                f32x2 P  = Eu * E;
                f32x2 den = P + 1.0f;
                f32x2 sg  = {__builtin_amdgcn_rcpf(den.x), __builtin_amdgcn_rcpf(den.y)};
                f32x2 compL = __builtin_elementwise_fma(ddL, sg, imL);
                f32x2 ee2 = {__builtin_amdgcn_exp2f(compL.x), __builtin_amdgcn_exp2f(compL.y)};
                f32x2 vv = ee2 + 1.0f;
                f32x2 lg = {__builtin_amdgcn_logf(vv.x), __builtin_amdgcn_logf(vv.y)};
                sa[q2] = lg.x;
                sb[q2] = lg.y;
            }
            a0[p] = cvtpk_bf16(sa[0], sa[1]);
            a1[p] = cvtpk_bf16(sb[0], sb[1]);
        }
        unsigned av0[4] = {a0[0], a0[1], a0[2], a0[3]};
        unsigned av1[4] = {a1[0], a1[1], a1[2], a1[3]};
        short8 af0 = *(short8*)av0;
        short8 af1 = *(short8*)av1;

        __builtin_amdgcn_s_setprio(1);
#pragma unroll
        for (int nb = 0; nb < 4; ++nb) {
            acc[0][nb] = __builtin_amdgcn_mfma_f32_16x16x32_bf16(af0, bfr[cur][nb], acc[0][nb], 0, 0, 0);
            acc[1][nb] = __builtin_amdgcn_mfma_f32_16x16x32_bf16(af1, bfr[cur][nb], acc[1][nb], 0, 0, 0);
        }
        __builtin_amdgcn_s_setprio(0);
    }

    __syncthreads();   // tables dead; smem becomes `red`

#pragma unroll
    for (int nb = 0; nb < 4; ++nb) {
        if (nb != w) {
            int idx = w - (w > nb ? 1 : 0);
#pragma unroll
            for (int m = 0; m < 2; ++m)
#pragma unroll
                for (int jj = 0; jj < 4; ++jj)
                    red[nb][idx][m * 16 + g * 4 + jj][r] = acc[m][nb][jj];
        }
    }
    __syncthreads();

#pragma unroll
    for (int m = 0; m < 2; ++m)
#pragma unroll
        for (int jj = 0; jj < 4; ++jj) {
            int lrow = m * 16 + g * 4 + jj;
            float c = acc[m][w][jj] + red[w][0][lrow][r]
                                    + red[w][1][lrow][r]
                                    + red[w][2][lrow][r];
            float gl = 0.5f * c * (1.0f + erff(c * 0.70710678118654752f));
            size_t base = ((size_t)(b * 1024 + i0 + lrow)) * 1024 + h * 64 + w * 16 + r;
            out[base] = x[base] + gl * zf;
        }
}

extern "C" void kernel_launch(void* const* d_in, const int* in_sizes, int n_in,
                              void* d_out, int out_size, void* d_ws, size_t ws_size,
                              hipStream_t stream) {
    const float* x      = (const float*)d_in[0];
    const float* mask   = (const float*)d_in[1];
    const float* Wq     = (const float*)d_in[2];
    const float* bq     = (const float*)d_in[3];
    const float* Wk     = (const float*)d_in[4];
    const float* bk     = (const float*)d_in[5];
    const float* Wv     = (const float*)d_in[6];
    const float* bv     = (const float*)d_in[7];
    const float* ln_g   = (const float*)d_in[8];
    const float* ln_b   = (const float*)d_in[9];
    const float* zf     = (const float*)d_in[10];
    const float* angle  = (const float*)d_in[11];
    float* out = (float*)d_out;

    unsigned short* xnb  = (unsigned short*)d_ws;   // 2M shorts
    unsigned short* vt   = xnb + 2097152;           // 2M shorts
    unsigned short* WvT  = vt + 2097152;            // 1M shorts
    unsigned short* WqkT = WvT + 1048576;           // 64K shorts
    float* qT    = (float*)(WqkT + 65536);          // 32K f32
    float* Ak    = qT + 32768;                      // 32K f32
    float* Bk    = Ak + 32768;                      // 32K f32
    float* Ek    = Bk + 32768;                      // 32K f32
    float* maskf = Ek + 32768;                      // 2K f32

    k_pre<<<BATCH * SEQ / 4 + 520, 256, 0, stream>>>(x, ln_g, ln_b, Wv, Wq, Wk, mask,
                                                     xnb, WvT, WqkT, maskf);
    k_gemm<<<544, 256, 0, stream>>>(xnb, WvT, WqkT, bv, bq, bk, angle, maskf,
                                    vt, qT, Ak, Bk, Ek);
    k_attn<<<1024, 256, 0, stream>>>(qT, Ak, Bk, Ek, vt, x, angle, zf, out);
}